// Round 11
// baseline (121.160 us; speedup 1.0000x reference)
//
#include <hip/hip_runtime.h>
#include <hip/hip_bf16.h>

typedef unsigned int u32;
typedef unsigned char u8;
typedef _Float16 f16;
typedef f16 f16x2 __attribute__((ext_vector_type(2)));
typedef short s16x8 __attribute__((ext_vector_type(8)));
typedef float f32x4 __attribute__((ext_vector_type(4)));

#define BB 64
#define LL 128
#define TT 64
#define NN 128
#define NM (NN*NN)   // 16384

__device__ __forceinline__ float sigf(float v) {
    return 1.0f / (1.0f + __expf(-v));
}

__device__ __forceinline__ float clip01(float v) {
    return fminf(fmaxf(v, 0.f), 1.f);
}

__device__ __forceinline__ u32 f2bf(float f) {   // f32 -> bf16 bits (RNE)
    u32 u = __builtin_bit_cast(u32, f);
    return (u + 0x7fffu + ((u >> 16) & 1u)) >> 16;
}

__device__ __forceinline__ float fdot2f(f16x2 wa, f16x2 xa, float ca) {
#if defined(__HIP_DEVICE_COMPILE__) && __has_builtin(__builtin_amdgcn_fdot2)
    return __builtin_amdgcn_fdot2(wa, xa, ca, false);
#else
    return ca + (float)wa[0] * (float)xa[0] + (float)wa[1] * (float)xa[1];
#endif
}

__device__ __forceinline__ u32 ud4(u32 a, u32 b, u32 c) {   // 4x u8 dot + acc
#if defined(__HIP_DEVICE_COMPILE__) && __has_builtin(__builtin_amdgcn_udot4)
    return __builtin_amdgcn_udot4(a, b, c, false);
#else
    return c + (a & 255u) * (b & 255u) + ((a >> 8) & 255u) * ((b >> 8) & 255u)
             + ((a >> 16) & 255u) * ((b >> 16) & 255u) + (a >> 24) * (b >> 24);
#endif
}

// 16B global -> LDS direct DMA (side-effecting: compiler cannot sink it).
__device__ __forceinline__ void gload_lds16(const u8* g, u8* lds) {
#if defined(__HIP_DEVICE_COMPILE__)
    __builtin_amdgcn_global_load_lds(
        (const __attribute__((address_space(1))) u32*)g,
        (__attribute__((address_space(3))) u32*)lds, 16, 0, 0);
#else
    (void)g; (void)lds;
#endif
}

// ---------------------------------------------------------------------------
// pack_w: sigmoid(ntp) -> bf16 A-fragment order for mfma_f32_16x16x32_bf16.
__global__ __launch_bounds__(256) void pack_w(const float* __restrict__ ntp,
                                              ushort* __restrict__ wpk) {
    const int g = blockIdx.x * 256 + threadIdx.x;   // 0..131071
    const int l = g & 63, h = (g >> 6) & 1, i = g >> 7;
    const int row = i * 16 + (l & 15);
    const int t0 = h * 32 + ((l >> 4) << 3);
    const float* src = ntp + row * 64 + t0;
    float4 f0 = *reinterpret_cast<const float4*>(src);
    float4 f1 = *reinterpret_cast<const float4*>(src + 4);
    float v[8] = {f0.x, f0.y, f0.z, f0.w, f1.x, f1.y, f1.z, f1.w};
    u32 o[4];
    #pragma unroll
    for (int q = 0; q < 4; ++q)
        o[q] = f2bf(sigf(v[2 * q])) | (f2bf(sigf(v[2 * q + 1])) << 16);
    uint4 ov; ov.x = o[0]; ov.y = o[1]; ov.z = o[2]; ov.w = o[3];
    *reinterpret_cast<uint4*>(wpk + (size_t)g * 8) = ov;
}

// ---------------------------------------------------------------------------
// pack_x: x -> bf16 B-fragment order.
__global__ __launch_bounds__(256) void pack_x(const float* __restrict__ x_all,
                                              ushort* __restrict__ xpk) {
    const int g = blockIdx.x * 256 + threadIdx.x;   // 0..65535
    const int l = g & 63, h = (g >> 6) & 1, j = (g >> 7) & 7, b = g >> 10;
    const int s = j * 16 + (l & 15);
    const int t0 = h * 32 + ((l >> 4) << 3);
    const float* src = x_all + ((size_t)b * LL + s) * TT + t0;
    float4 f0 = *reinterpret_cast<const float4*>(src);
    float4 f1 = *reinterpret_cast<const float4*>(src + 4);
    float v[8] = {f0.x, f0.y, f0.z, f0.w, f1.x, f1.y, f1.z, f1.w};
    u32 o[4];
    #pragma unroll
    for (int q = 0; q < 4; ++q)
        o[q] = f2bf(v[2 * q]) | (f2bf(v[2 * q + 1]) << 16);
    uint4 ov; ov.x = o[0]; ov.y = o[1]; ov.z = o[2]; ov.w = o[3];
    *reinterpret_cast<uint4*>(xpk + (size_t)g * 8) = ov;
}

// ---------------------------------------------------------------------------
// gemm_mfma, layout R:
//   npc byte(b,s,n,m) = b<<21 | (s>>4)<<18 | (s&15)<<14
//                       | ((m>>4) + 8*(n>>6))<<10 | (n&63)<<4 | (m&15)
// Store-side scatter resolved by wave-private LDS transpose (skewed), then
// coalesced dwordx4 flush. Grid 1024 wgs = (b 64) x (nb 16).
__global__ __launch_bounds__(256) void gemm_mfma(const ushort* __restrict__ wpk,
                                                 const ushort* __restrict__ xpk,
                                                 u8* __restrict__ npc) {
    __shared__ __align__(16) u8 stg[4][16384];
    const int b = blockIdx.x >> 4;
    const int nb = blockIdx.x & 15;
    const int wv = threadIdx.x >> 6, l = threadIdx.x & 63;

    uint4 xf[8][2];
    #pragma unroll
    for (int j = 0; j < 8; ++j)
        #pragma unroll
        for (int h = 0; h < 2; ++h)
            xf[j][h] = *reinterpret_cast<const uint4*>(
                xpk + (size_t)(((b * 8 + j) * 2 + h) * 64 + l) * 8);

    const int c = l & 15, r0 = (l >> 4) * 4;
    u8* stw = stg[wv];
    const int khi  = (nb >> 3) * 8;
    const int nlow = (nb & 7) * 8;

    for (int mg2 = 0; mg2 < 2; ++mg2) {
        const int mg = wv * 2 + mg2;
        #pragma unroll
        for (int n_l = 0; n_l < 8; ++n_l) {
            const int i = (nb * 8 + n_l) * 8 + mg;   // tile index
            uint4 a0 = *reinterpret_cast<const uint4*>(wpk + (size_t)((i * 2 + 0) * 64 + l) * 8);
            uint4 a1 = *reinterpret_cast<const uint4*>(wpk + (size_t)((i * 2 + 1) * 64 + l) * 8);
            const f32x4 z = {0.f, 0.f, 0.f, 0.f};
            f32x4 acc[8];
            #pragma unroll
            for (int j = 0; j < 8; ++j)
                acc[j] = __builtin_amdgcn_mfma_f32_16x16x32_bf16(
                    __builtin_bit_cast(s16x8, a0), __builtin_bit_cast(s16x8, xf[j][0]), z, 0, 0, 0);
            #pragma unroll
            for (int j = 0; j < 8; ++j)
                acc[j] = __builtin_amdgcn_mfma_f32_16x16x32_bf16(
                    __builtin_bit_cast(s16x8, a1), __builtin_bit_cast(s16x8, xf[j][1]), acc[j], 0, 0, 0);

            const int sk = (((n_l + c) & 7) << 4) + r0;
            #pragma unroll
            for (int j = 0; j < 8; ++j) {
                u32 w = 0;
                #pragma unroll
                for (int r = 0; r < 4; ++r) {
                    float q = clip01(acc[j][r]) * 255.f + 0.5f;
                    w |= ((u32)q) << (8 * r);
                }
                *reinterpret_cast<u32*>(stw + j * 2048 + c * 128 + sk) = w;
            }
        }
        asm volatile("s_waitcnt lgkmcnt(0)" ::: "memory");
        __builtin_amdgcn_sched_barrier(0);

        // flush: 16 coalesced dwordx4 stores (8-lane 128B runs)
        const int nr = l & 7;
        #pragma unroll
        for (int j = 0; j < 8; ++j) {
            #pragma unroll
            for (int half = 0; half < 2; ++half) {
                const int cc = half * 8 + (l >> 3);
                uint4 v = *reinterpret_cast<const uint4*>(
                    stw + j * 2048 + cc * 128 + (((nr + cc) & 7) << 4));
                *reinterpret_cast<uint4*>(npc + ((size_t)b << 21) + ((size_t)j << 18)
                    + ((size_t)cc << 14) + ((size_t)(mg + khi) << 10)
                    + ((nlow + nr) << 4)) = v;
            }
        }
        asm volatile("s_waitcnt lgkmcnt(0)" ::: "memory");
        __builtin_amdgcn_sched_barrier(0);
    }
}

// ---------------------------------------------------------------------------
// recur7: one wave per batch; lane l owns rows n=l, 64+l; 64 udot4/step.
// npc staged into a 3-slot LDS ring via global_load_lds (cannot be sunk by
// the compiler, no VGPR outputs); counted s_waitcnt vmcnt(32) per step keeps
// 2 future steps permanently in flight. Lane reads its 16B chunks back with
// conflict-free ds_read_b128.
__global__ __launch_bounds__(64, 1) void recur7(const float* __restrict__ x_all,
                                                const float* __restrict__ tp,
                                                const u8* __restrict__ npc,
                                                float* __restrict__ outp) {
    __shared__ __align__(16) u8 npc_lds[3 * 16384];   // 48 KB ring
    __shared__ __align__(16) u8 prev_lds[2][128];
    __shared__ float masks_lds[128];
    __shared__ float tpc_lds[128];
    __shared__ float x0_lds[64];

    const int b = blockIdx.x, l = threadIdx.x;
    const u8* npcg = npc + ((size_t)b << 21);

    // one-time staging of x0 / masks
    x0_lds[l] = x_all[(size_t)b * 8192 + l];
    masks_lds[l]      = x_all[(size_t)b * 8192 + l * 64 + 63];
    masks_lds[64 + l] = x_all[(size_t)b * 8192 + (64 + l) * 64 + 63];
    asm volatile("s_waitcnt lgkmcnt(0)" ::: "memory");
    __builtin_amdgcn_sched_barrier(0);

    // tpc (exact f32): lane l -> n=l and n=64+l
    float a0 = 0.f, a1 = 0.f;
    #pragma unroll
    for (int t4 = 0; t4 < 16; ++t4) {
        float4 xv = *reinterpret_cast<const float4*>(x0_lds + t4 * 4);
        float4 w0 = *reinterpret_cast<const float4*>(tp + l * 64 + t4 * 4);
        float4 w1 = *reinterpret_cast<const float4*>(tp + (64 + l) * 64 + t4 * 4);
        a0 += sigf(w0.x) * xv.x; a0 += sigf(w0.y) * xv.y;
        a0 += sigf(w0.z) * xv.z; a0 += sigf(w0.w) * xv.w;
        a1 += sigf(w1.x) * xv.x; a1 += sigf(w1.y) * xv.y;
        a1 += sigf(w1.z) * xv.z; a1 += sigf(w1.w) * xv.w;
    }
    tpc_lds[l] = a0; tpc_lds[64 + l] = a1;
    float out_r = a0;                       // lane 0 holds tpc[0]
    // drain ALL regular vm loads so counted vmcnt below is exact
    asm volatile("s_waitcnt vmcnt(0) lgkmcnt(0)" ::: "memory");
    __builtin_amdgcn_sched_barrier(0);

    // stage step T's 16KB into LDS slot at byte offset SLOT_OFF (16 vm ops)
#define STAGE(SLOT_OFF, T) do { \
        int _t = (T) <= 127 ? (T) : 127; \
        const u8* _src = npcg + ((size_t)(_t >> 4) << 18) \
                              + ((size_t)(_t & 15) << 14) + ((u32)l << 4); \
        _Pragma("unroll") \
        for (int _k = 0; _k < 16; ++_k) \
            gload_lds16(_src + _k * 1024, &npc_lds[(SLOT_OFF) + _k * 1024]); \
        __builtin_amdgcn_sched_barrier(0); \
    } while (0)

    STAGE(0, 1); STAGE(16384, 2); STAGE(32768, 3);    // 48 outstanding

    // ---- step 1: cur1 = clip01(npc1 . tpc), tpc in f32 (unclipped range) ----
    {
        asm volatile("s_waitcnt vmcnt(32)" ::: "memory");   // slot0 landed
        __builtin_amdgcn_sched_barrier(0);
        uint4 nk[16];
        #pragma unroll
        for (int k = 0; k < 16; ++k)
            nk[k] = *reinterpret_cast<const uint4*>(&npc_lds[k * 1024 + l * 16]);
        float s0f = 0.f, s1f = 0.f;
        #pragma unroll
        for (int k = 0; k < 8; ++k) {
            u32 ax[4] = {nk[k].x, nk[k].y, nk[k].z, nk[k].w};
            u32 bx[4] = {nk[k + 8].x, nk[k + 8].y, nk[k + 8].z, nk[k + 8].w};
            #pragma unroll
            for (int w = 0; w < 4; ++w) {
                float4 tv = *reinterpret_cast<const float4*>(tpc_lds + k * 16 + w * 4);
                u32 aw = ax[w], bw = bx[w];
                s0f += (float)(aw & 255u) * tv.x + (float)((aw >> 8) & 255u) * tv.y
                     + (float)((aw >> 16) & 255u) * tv.z + (float)(aw >> 24) * tv.w;
                s1f += (float)(bw & 255u) * tv.x + (float)((bw >> 8) & 255u) * tv.y
                     + (float)((bw >> 16) & 255u) * tv.z + (float)(bw >> 24) * tv.w;
            }
        }
        float c0 = clip01(s0f * (1.f / 255.f));
        float c1 = clip01(s1f * (1.f / 255.f));
        float mk = masks_lds[1];
        if (l == 0) out_r = out_r * mk + c0 * (1.f - mk);
        prev_lds[0][l]      = (u8)(c0 * 255.f + 0.5f);
        prev_lds[0][64 + l] = (u8)(c1 * 255.f + 0.5f);
        asm volatile("s_waitcnt lgkmcnt(0)" ::: "memory");
        __builtin_amdgcn_sched_barrier(0);
    }
    STAGE(0, 4);                                      // refill consumed slot

    int p = 0;

#define STEP(SLOT_OFF, S) do { \
        asm volatile("s_waitcnt vmcnt(32)" ::: "memory"); \
        __builtin_amdgcn_sched_barrier(0); \
        uint4 nk[16]; \
        _Pragma("unroll") \
        for (int _k = 0; _k < 16; ++_k) \
            nk[_k] = *reinterpret_cast<const uint4*>(&npc_lds[(SLOT_OFF) + _k * 1024 + l * 16]); \
        uint4 pv[8]; \
        _Pragma("unroll") \
        for (int _q = 0; _q < 8; ++_q) \
            pv[_q] = *reinterpret_cast<const uint4*>(&prev_lds[p][_q * 16]); \
        float mk = masks_lds[(S)]; \
        u32 s0 = 0, t0 = 0, s1 = 0, t1 = 0; \
        _Pragma("unroll") \
        for (int _k = 0; _k < 4; ++_k) { \
            s0 = ud4(nk[_k].x, pv[_k].x, s0); s0 = ud4(nk[_k].y, pv[_k].y, s0); \
            s0 = ud4(nk[_k].z, pv[_k].z, s0); s0 = ud4(nk[_k].w, pv[_k].w, s0); \
        } \
        _Pragma("unroll") \
        for (int _k = 4; _k < 8; ++_k) { \
            t0 = ud4(nk[_k].x, pv[_k].x, t0); t0 = ud4(nk[_k].y, pv[_k].y, t0); \
            t0 = ud4(nk[_k].z, pv[_k].z, t0); t0 = ud4(nk[_k].w, pv[_k].w, t0); \
        } \
        _Pragma("unroll") \
        for (int _k = 8; _k < 12; ++_k) { \
            s1 = ud4(nk[_k].x, pv[_k - 8].x, s1); s1 = ud4(nk[_k].y, pv[_k - 8].y, s1); \
            s1 = ud4(nk[_k].z, pv[_k - 8].z, s1); s1 = ud4(nk[_k].w, pv[_k - 8].w, s1); \
        } \
        _Pragma("unroll") \
        for (int _k = 12; _k < 16; ++_k) { \
            t1 = ud4(nk[_k].x, pv[_k - 8].x, t1); t1 = ud4(nk[_k].y, pv[_k - 8].y, t1); \
            t1 = ud4(nk[_k].z, pv[_k - 8].z, t1); t1 = ud4(nk[_k].w, pv[_k - 8].w, t1); \
        } \
        float c0 = fminf((float)(s0 + t0) * (1.f / 65025.f), 1.f); \
        float c1 = fminf((float)(s1 + t1) * (1.f / 65025.f), 1.f); \
        u32 q0 = (u32)(c0 * 255.f + 0.5f), q1 = (u32)(c1 * 255.f + 0.5f); \
        if (l == 0) out_r = out_r * mk + c0 * (1.f - mk); \
        prev_lds[p ^ 1][l]      = (u8)q0; \
        prev_lds[p ^ 1][64 + l] = (u8)q1; \
        asm volatile("s_waitcnt lgkmcnt(0)" ::: "memory"); \
        __builtin_amdgcn_sched_barrier(0); \
        p ^= 1; \
    } while (0)

    // steps 2..124: 41 iterations x 3 steps; slot for step s = ((s-1)%3)*16K,
    // each STEP refills the slot it just consumed with step s+3.
    for (int g = 0; g < 41; ++g) {
        const int s = 2 + 3 * g;
        STEP(16384, s);     STAGE(16384, s + 3);
        STEP(32768, s + 1); STAGE(32768, s + 4);
        STEP(0,     s + 2); STAGE(0,     s + 5);
    }
    // tail: steps 125..127; dummy clamped stages keep vmcnt counting uniform
    STEP(16384, 125); STAGE(16384, 127);
    STEP(32768, 126); STAGE(32768, 127);
    STEP(0,     127); STAGE(0,     127);
    asm volatile("s_waitcnt vmcnt(0)" ::: "memory");
    __builtin_amdgcn_sched_barrier(0);

#undef STEP
#undef STAGE

    if (l == 0) outp[b] = out_r;
}

// ---------------------------------------------------------------------------
// Fallback (known-passing round-2 kernel): fused recurrence, 2 MB ws.
__global__ __launch_bounds__(256) void sig_transpose(const float* __restrict__ ntp,
                                                     u32* __restrict__ out) {
    __shared__ float lds[64 * 65];
    const int nm0 = blockIdx.x * 64;
    const int tid = threadIdx.x;
    #pragma unroll
    for (int it = 0; it < 16; ++it) {
        int idx = it * 256 + tid;
        int r = idx >> 6, c = idx & 63;
        lds[r * 65 + c] = sigf(ntp[(nm0 + r) * 64 + c]);
    }
    __syncthreads();
    #pragma unroll
    for (int it = 0; it < 8; ++it) {
        int o = it * 256 + tid;
        int tpi = o >> 6, r = o & 63;
        f16x2 h;
        h[0] = (f16)lds[r * 65 + 2 * tpi];
        h[1] = (f16)lds[r * 65 + 2 * tpi + 1];
        out[tpi * NM + nm0 + r] = __builtin_bit_cast(u32, h);
    }
}

__global__ __launch_bounds__(1024) void grammar_fused(
    const float* __restrict__ x_all,
    const float* __restrict__ tp,
    const u32*  __restrict__ ntpT2,
    float* __restrict__ outp) {
    __shared__ float x_lds[LL * TT];
    __shared__ float prevbuf[2][NN];
    __shared__ u32 x2_lds[2][32];

    const int b = blockIdx.x;
    const int tid = threadIdx.x;
    const int lane16 = tid & 15;
    const int g = tid >> 4;
    const int mbase = lane16 * 8;

    const float* xb = x_all + b * (LL * TT);
    #pragma unroll
    for (int it = 0; it < 8; ++it) {
        int idx = it * 1024 + tid;
        x_lds[idx] = xb[idx];
    }
    __syncthreads();

    if (tid < NN) {
        float acc = 0.f;
        #pragma unroll 8
        for (int t = 0; t < TT; ++t)
            acc += sigf(tp[tid * TT + t]) * x_lds[t];
        prevbuf[0][tid] = acc;
    }
    __syncthreads();
    float out_r = 0.f;
    if (tid == 0) out_r = prevbuf[0][0];

    int p = 0;
    for (int i0 = 1; i0 < LL; i0 += 2) {
        const int ns = (LL - i0) >= 2 ? 2 : 1;
        if (tid < 64) {
            int s = tid >> 5, tpi = tid & 31;
            f16x2 h;
            if (s < ns) {
                h[0] = (f16)x_lds[(i0 + s) * TT + 2 * tpi];
                h[1] = (f16)x_lds[(i0 + s) * TT + 2 * tpi + 1];
            } else {
                h[0] = (f16)0.f; h[1] = (f16)0.f;
            }
            x2_lds[s][tpi] = __builtin_bit_cast(u32, h);
        }
        __syncthreads();

        float acc[2][2][8];
        #pragma unroll
        for (int k = 0; k < 2; ++k)
            #pragma unroll
            for (int s = 0; s < 2; ++s)
                #pragma unroll
                for (int j = 0; j < 8; ++j) acc[k][s][j] = 0.f;

        #pragma unroll 2
        for (int tpi = 0; tpi < 32; ++tpi) {
            f16x2 xv0 = __builtin_bit_cast(f16x2, x2_lds[0][tpi]);
            f16x2 xv1 = __builtin_bit_cast(f16x2, x2_lds[1][tpi]);
            const u32* base = ntpT2 + tpi * NM + 8 * tid;
            #pragma unroll
            for (int k = 0; k < 2; ++k) {
                uint4 w0 = *reinterpret_cast<const uint4*>(base + 8192 * k);
                uint4 w1 = *reinterpret_cast<const uint4*>(base + 8192 * k + 4);
                u32 wv[8] = {w0.x, w0.y, w0.z, w0.w, w1.x, w1.y, w1.z, w1.w};
                #pragma unroll
                for (int j = 0; j < 8; ++j) {
                    f16x2 w = __builtin_bit_cast(f16x2, wv[j]);
                    acc[k][0][j] = fdot2f(w, xv0, acc[k][0][j]);
                    acc[k][1][j] = fdot2f(w, xv1, acc[k][1][j]);
                }
            }
        }

        for (int s = 0; s < ns; ++s) {
            float4 pv0 = *reinterpret_cast<const float4*>(&prevbuf[p][mbase]);
            float4 pv1 = *reinterpret_cast<const float4*>(&prevbuf[p][mbase + 4]);
            float pvv[8] = {pv0.x, pv0.y, pv0.z, pv0.w, pv1.x, pv1.y, pv1.z, pv1.w};
            #pragma unroll
            for (int k = 0; k < 2; ++k) {
                float part = 0.f;
                #pragma unroll
                for (int j = 0; j < 8; ++j) {
                    float npcv = clip01(acc[k][s][j]);
                    part += npcv * pvv[j];
                }
                part += __shfl_xor(part, 1);
                part += __shfl_xor(part, 2);
                part += __shfl_xor(part, 4);
                part += __shfl_xor(part, 8);
                if (lane16 == 0) {
                    float c = clip01(part);
                    prevbuf[p ^ 1][g + 64 * k] = c;
                    if (tid == 0 && k == 0) {
                        float mask = x_lds[(i0 + s) * TT + 63];
                        out_r = out_r * mask + c * (1.f - mask);
                    }
                }
            }
            p ^= 1;
            __syncthreads();
        }
    }

    if (tid == 0) outp[b] = out_r;
}

// ---------------------------------------------------------------------------
extern "C" void kernel_launch(void* const* d_in, const int* in_sizes, int n_in,
                              void* d_out, int out_size, void* d_ws, size_t ws_size,
                              hipStream_t stream) {
    const float* input_tensor = (const float*)d_in[0];   // [64][128][64]
    const float* term_prod    = (const float*)d_in[1];   // [128][64]
    const float* nonterm_prod = (const float*)d_in[2];   // [128][128][64]
    float* outp = (float*)d_out;                         // [64]

    const size_t MB = 1024 * 1024;
    const size_t NPC_BYTES = 128 * MB;   // layout R
    const size_t WPK_BYTES = 2 * MB;     // bf16 A-frags
    const size_t XPK_BYTES = 1 * MB;     // bf16 B-frags

    if (ws_size >= NPC_BYTES + WPK_BYTES + XPK_BYTES + MB) {
        u8* npcbuf  = (u8*)d_ws;
        ushort* wpk = (ushort*)((char*)d_ws + NPC_BYTES);
        ushort* xpk = (ushort*)((char*)d_ws + NPC_BYTES + WPK_BYTES);
        pack_w<<<512, 256, 0, stream>>>(nonterm_prod, wpk);
        pack_x<<<256, 256, 0, stream>>>(input_tensor, xpk);
        gemm_mfma<<<1024, 256, 0, stream>>>(wpk, xpk, npcbuf);
        recur7<<<BB, 64, 0, stream>>>(input_tensor, term_prod, npcbuf, outp);
    } else {
        u32* ntpT2 = (u32*)d_ws;
        sig_transpose<<<256, 256, 0, stream>>>(nonterm_prod, ntpT2);
        grammar_fused<<<BB, 1024, 0, stream>>>(input_tensor, term_prod, ntpT2, outp);
    }
}

// Round 12
// 81.116 us; speedup vs baseline: 1.4937x; 1.4937x over previous
//
#include <hip/hip_runtime.h>
#include <hip/hip_bf16.h>

typedef unsigned int u32;
typedef unsigned char u8;
typedef _Float16 f16;
typedef f16 f16x2 __attribute__((ext_vector_type(2)));
typedef short s16x8 __attribute__((ext_vector_type(8)));
typedef float f32x4 __attribute__((ext_vector_type(4)));

#define BB 64
#define LL 128
#define TT 64
#define NN 128
#define NM (NN*NN)   // 16384

__device__ __forceinline__ float sigf(float v) {
    return 1.0f / (1.0f + __expf(-v));
}

__device__ __forceinline__ float clip01(float v) {
    return fminf(fmaxf(v, 0.f), 1.f);
}

__device__ __forceinline__ u32 f2bf(float f) {   // f32 -> bf16 bits (RNE)
    u32 u = __builtin_bit_cast(u32, f);
    return (u + 0x7fffu + ((u >> 16) & 1u)) >> 16;
}

__device__ __forceinline__ float fdot2f(f16x2 wa, f16x2 xa, float ca) {
#if defined(__HIP_DEVICE_COMPILE__) && __has_builtin(__builtin_amdgcn_fdot2)
    return __builtin_amdgcn_fdot2(wa, xa, ca, false);
#else
    return ca + (float)wa[0] * (float)xa[0] + (float)wa[1] * (float)xa[1];
#endif
}

__device__ __forceinline__ u32 ud4(u32 a, u32 b, u32 c) {   // 4x u8 dot + acc
#if defined(__HIP_DEVICE_COMPILE__) && __has_builtin(__builtin_amdgcn_udot4)
    return __builtin_amdgcn_udot4(a, b, c, false);
#else
    return c + (a & 255u) * (b & 255u) + ((a >> 8) & 255u) * ((b >> 8) & 255u)
             + ((a >> 16) & 255u) * ((b >> 16) & 255u) + (a >> 24) * (b >> 24);
#endif
}

// ---------------------------------------------------------------------------
// pack_w: sigmoid(ntp) -> bf16 A-fragment order for mfma_f32_16x16x32_bf16.
__global__ __launch_bounds__(256) void pack_w(const float* __restrict__ ntp,
                                              ushort* __restrict__ wpk) {
    const int g = blockIdx.x * 256 + threadIdx.x;   // 0..131071
    const int l = g & 63, h = (g >> 6) & 1, i = g >> 7;
    const int row = i * 16 + (l & 15);
    const int t0 = h * 32 + ((l >> 4) << 3);
    const float* src = ntp + row * 64 + t0;
    float4 f0 = *reinterpret_cast<const float4*>(src);
    float4 f1 = *reinterpret_cast<const float4*>(src + 4);
    float v[8] = {f0.x, f0.y, f0.z, f0.w, f1.x, f1.y, f1.z, f1.w};
    u32 o[4];
    #pragma unroll
    for (int q = 0; q < 4; ++q)
        o[q] = f2bf(sigf(v[2 * q])) | (f2bf(sigf(v[2 * q + 1])) << 16);
    uint4 ov; ov.x = o[0]; ov.y = o[1]; ov.z = o[2]; ov.w = o[3];
    *reinterpret_cast<uint4*>(wpk + (size_t)g * 8) = ov;
}

// ---------------------------------------------------------------------------
// pack_x: x -> bf16 B-fragment order.
__global__ __launch_bounds__(256) void pack_x(const float* __restrict__ x_all,
                                              ushort* __restrict__ xpk) {
    const int g = blockIdx.x * 256 + threadIdx.x;   // 0..65535
    const int l = g & 63, h = (g >> 6) & 1, j = (g >> 7) & 7, b = g >> 10;
    const int s = j * 16 + (l & 15);
    const int t0 = h * 32 + ((l >> 4) << 3);
    const float* src = x_all + ((size_t)b * LL + s) * TT + t0;
    float4 f0 = *reinterpret_cast<const float4*>(src);
    float4 f1 = *reinterpret_cast<const float4*>(src + 4);
    float v[8] = {f0.x, f0.y, f0.z, f0.w, f1.x, f1.y, f1.z, f1.w};
    u32 o[4];
    #pragma unroll
    for (int q = 0; q < 4; ++q)
        o[q] = f2bf(v[2 * q]) | (f2bf(v[2 * q + 1]) << 16);
    uint4 ov; ov.x = o[0]; ov.y = o[1]; ov.z = o[2]; ov.w = o[3];
    *reinterpret_cast<uint4*>(xpk + (size_t)g * 8) = ov;
}

// ---------------------------------------------------------------------------
// gemm_mfma, layout R:
//   npc byte(b,s,n,m) = b<<21 | (s>>4)<<18 | (s&15)<<14
//                       | ((m>>4) + 8*(n>>6))<<10 | (n&63)<<4 | (m&15)
// Store-side scatter resolved by wave-private LDS transpose (skewed), then
// coalesced dwordx4 flush. Grid 1024 wgs = (b 64) x (nb 16).
__global__ __launch_bounds__(256) void gemm_mfma(const ushort* __restrict__ wpk,
                                                 const ushort* __restrict__ xpk,
                                                 u8* __restrict__ npc) {
    __shared__ __align__(16) u8 stg[4][16384];
    const int b = blockIdx.x >> 4;
    const int nb = blockIdx.x & 15;
    const int wv = threadIdx.x >> 6, l = threadIdx.x & 63;

    uint4 xf[8][2];
    #pragma unroll
    for (int j = 0; j < 8; ++j)
        #pragma unroll
        for (int h = 0; h < 2; ++h)
            xf[j][h] = *reinterpret_cast<const uint4*>(
                xpk + (size_t)(((b * 8 + j) * 2 + h) * 64 + l) * 8);

    const int c = l & 15, r0 = (l >> 4) * 4;
    u8* stw = stg[wv];
    const int khi  = (nb >> 3) * 8;
    const int nlow = (nb & 7) * 8;

    for (int mg2 = 0; mg2 < 2; ++mg2) {
        const int mg = wv * 2 + mg2;
        #pragma unroll
        for (int n_l = 0; n_l < 8; ++n_l) {
            const int i = (nb * 8 + n_l) * 8 + mg;   // tile index
            uint4 a0 = *reinterpret_cast<const uint4*>(wpk + (size_t)((i * 2 + 0) * 64 + l) * 8);
            uint4 a1 = *reinterpret_cast<const uint4*>(wpk + (size_t)((i * 2 + 1) * 64 + l) * 8);
            const f32x4 z = {0.f, 0.f, 0.f, 0.f};
            f32x4 acc[8];
            #pragma unroll
            for (int j = 0; j < 8; ++j)
                acc[j] = __builtin_amdgcn_mfma_f32_16x16x32_bf16(
                    __builtin_bit_cast(s16x8, a0), __builtin_bit_cast(s16x8, xf[j][0]), z, 0, 0, 0);
            #pragma unroll
            for (int j = 0; j < 8; ++j)
                acc[j] = __builtin_amdgcn_mfma_f32_16x16x32_bf16(
                    __builtin_bit_cast(s16x8, a1), __builtin_bit_cast(s16x8, xf[j][1]), acc[j], 0, 0, 0);

            const int sk = (((n_l + c) & 7) << 4) + r0;
            #pragma unroll
            for (int j = 0; j < 8; ++j) {
                u32 w = 0;
                #pragma unroll
                for (int r = 0; r < 4; ++r) {
                    float q = clip01(acc[j][r]) * 255.f + 0.5f;
                    w |= ((u32)q) << (8 * r);
                }
                *reinterpret_cast<u32*>(stw + j * 2048 + c * 128 + sk) = w;
            }
        }
        asm volatile("s_waitcnt lgkmcnt(0)" ::: "memory");
        __builtin_amdgcn_sched_barrier(0);

        // flush: 16 coalesced dwordx4 stores (8-lane 128B runs)
        const int nr = l & 7;
        #pragma unroll
        for (int j = 0; j < 8; ++j) {
            #pragma unroll
            for (int half = 0; half < 2; ++half) {
                const int cc = half * 8 + (l >> 3);
                uint4 v = *reinterpret_cast<const uint4*>(
                    stw + j * 2048 + cc * 128 + (((nr + cc) & 7) << 4));
                *reinterpret_cast<uint4*>(npc + ((size_t)b << 21) + ((size_t)j << 18)
                    + ((size_t)cc << 14) + ((size_t)(mg + khi) << 10)
                    + ((nlow + nr) << 4)) = v;
            }
        }
        asm volatile("s_waitcnt lgkmcnt(0)" ::: "memory");
        __builtin_amdgcn_sched_barrier(0);
    }
}

// ---------------------------------------------------------------------------
// recur8: 256 threads (4 waves) per batch. Thread tid: row n = tid>>1,
// m-half h = tid&1 -> 4x16B loads/step (2x512B coalesced runs per wave),
// 16 udot4, partner reduce via shfl_xor(1) (intra-wave). Raw s_barrier with
// lgkmcnt-only drain keeps prefetched vm loads in flight; compiler inserts
// counted vmcnt before each set's first use. Depth-4 named-set prefetch.
__global__ __launch_bounds__(256, 1) void recur8(const float* __restrict__ x_all,
                                                 const float* __restrict__ tp,
                                                 const u8* __restrict__ npc,
                                                 float* __restrict__ outp) {
    __shared__ __align__(16) u8 prev_lds[2][NN];
    __shared__ float masks_lds[LL];
    __shared__ float tpc_lds[NN];
    __shared__ float x0_lds[TT];

    const int b = blockIdx.x, tid = threadIdx.x;
    const int n = tid >> 1, h = tid & 1;
    const int koff = (n >> 6) * 8 + h * 4;
    const u8* npcl = npc + ((size_t)b << 21) + (u32)koff * 1024 + (u32)(n & 63) * 16;

    if (tid < 128) masks_lds[tid] = x_all[(size_t)b * 8192 + tid * 64 + 63];
    else if (tid < 192) x0_lds[tid - 128] = x_all[(size_t)b * 8192 + (tid - 128)];
    __syncthreads();

#define LOADSET(R, T) do { \
        int _t = (T) <= 127 ? (T) : 127; \
        const u8* _p = npcl + ((size_t)(_t >> 4) << 18) + ((size_t)(_t & 15) << 14); \
        R[0] = *reinterpret_cast<const uint4*>(_p); \
        R[1] = *reinterpret_cast<const uint4*>(_p + 1024); \
        R[2] = *reinterpret_cast<const uint4*>(_p + 2048); \
        R[3] = *reinterpret_cast<const uint4*>(_p + 3072); \
        asm volatile("" ::: "memory"); \
    } while (0)

    uint4 nA[4], nB[4], nC[4], nD[4];
    LOADSET(nA, 1); LOADSET(nB, 2); LOADSET(nC, 3); LOADSET(nD, 4);

    // tpc (exact f32): thread tid < 128 computes row tid; hides prefetch latency
    float out_r = 0.f;
    if (tid < 128) {
        float a = 0.f;
        #pragma unroll
        for (int t4 = 0; t4 < 16; ++t4) {
            float4 xv = *reinterpret_cast<const float4*>(x0_lds + t4 * 4);
            float4 w0 = *reinterpret_cast<const float4*>(tp + tid * 64 + t4 * 4);
            a += sigf(w0.x) * xv.x; a += sigf(w0.y) * xv.y;
            a += sigf(w0.z) * xv.z; a += sigf(w0.w) * xv.w;
        }
        tpc_lds[tid] = a;
        if (tid == 0) out_r = a;            // out0 = tpc[0]
    }
    asm volatile("s_waitcnt lgkmcnt(0)" ::: "memory");
    __builtin_amdgcn_s_barrier();
    __builtin_amdgcn_sched_barrier(0);

    // ---- step 1: cur1 = clip01(npc1 . tpc), tpc in f32 (unclipped range) ----
    {
        float sf = 0.f;
        #pragma unroll
        for (int j = 0; j < 4; ++j) {
            u32 cw[4] = {nA[j].x, nA[j].y, nA[j].z, nA[j].w};
            #pragma unroll
            for (int w = 0; w < 4; ++w) {
                float4 tv = *reinterpret_cast<const float4*>(
                    tpc_lds + h * 64 + j * 16 + w * 4);
                u32 aw = cw[w];
                sf += (float)(aw & 255u) * tv.x + (float)((aw >> 8) & 255u) * tv.y
                    + (float)((aw >> 16) & 255u) * tv.z + (float)(aw >> 24) * tv.w;
            }
        }
        float tot = sf + __shfl_xor(sf, 1);
        float c0 = clip01(tot * (1.f / 255.f));
        if (h == 0) prev_lds[0][n] = (u8)(c0 * 255.f + 0.5f);
        if (tid == 0) {
            float mk = masks_lds[1];
            out_r = out_r * mk + c0 * (1.f - mk);
        }
        asm volatile("s_waitcnt lgkmcnt(0)" ::: "memory");
        __builtin_amdgcn_s_barrier();
        __builtin_amdgcn_sched_barrier(0);
    }
    LOADSET(nA, 5);

    int p = 0;

#define STEP(R, S) do { \
        uint4 pv[4]; \
        _Pragma("unroll") \
        for (int _q = 0; _q < 4; ++_q) \
            pv[_q] = *reinterpret_cast<const uint4*>(&prev_lds[p][h * 64 + _q * 16]); \
        float mk = masks_lds[(S)]; \
        u32 s0 = 0, s1 = 0; \
        s0 = ud4(R[0].x, pv[0].x, s0); s0 = ud4(R[0].y, pv[0].y, s0); \
        s0 = ud4(R[0].z, pv[0].z, s0); s0 = ud4(R[0].w, pv[0].w, s0); \
        s1 = ud4(R[1].x, pv[1].x, s1); s1 = ud4(R[1].y, pv[1].y, s1); \
        s1 = ud4(R[1].z, pv[1].z, s1); s1 = ud4(R[1].w, pv[1].w, s1); \
        s0 = ud4(R[2].x, pv[2].x, s0); s0 = ud4(R[2].y, pv[2].y, s0); \
        s0 = ud4(R[2].z, pv[2].z, s0); s0 = ud4(R[2].w, pv[2].w, s0); \
        s1 = ud4(R[3].x, pv[3].x, s1); s1 = ud4(R[3].y, pv[3].y, s1); \
        s1 = ud4(R[3].z, pv[3].z, s1); s1 = ud4(R[3].w, pv[3].w, s1); \
        float sf = (float)(s0 + s1); \
        float tot = sf + __shfl_xor(sf, 1); \
        float c0 = fminf(tot * (1.f / 65025.f), 1.f); \
        if (h == 0) prev_lds[p ^ 1][n] = (u8)(c0 * 255.f + 0.5f); \
        if (tid == 0) out_r = out_r * mk + c0 * (1.f - mk); \
        asm volatile("s_waitcnt lgkmcnt(0)" ::: "memory"); \
        __builtin_amdgcn_s_barrier(); \
        __builtin_amdgcn_sched_barrier(0); \
        p ^= 1; \
    } while (0)

    // steps 2..125: 31 iterations x 4 steps, rotation B,C,D,A; loads 4 ahead
    for (int g = 0; g < 31; ++g) {
        const int s = 2 + 4 * g;
        STEP(nB, s);     LOADSET(nB, s + 4);
        STEP(nC, s + 1); LOADSET(nC, s + 5);
        STEP(nD, s + 2); LOADSET(nD, s + 6);
        STEP(nA, s + 3); LOADSET(nA, s + 7);
    }
    // tail: steps 126 (nB), 127 (nC); nD/nA hold dead clamped loads
    STEP(nB, 126);
    STEP(nC, 127);

#undef STEP
#undef LOADSET

    if (tid == 0) outp[b] = out_r;
}

// ---------------------------------------------------------------------------
// Fallback (known-passing round-2 kernel): fused recurrence, 2 MB ws.
__global__ __launch_bounds__(256) void sig_transpose(const float* __restrict__ ntp,
                                                     u32* __restrict__ out) {
    __shared__ float lds[64 * 65];
    const int nm0 = blockIdx.x * 64;
    const int tid = threadIdx.x;
    #pragma unroll
    for (int it = 0; it < 16; ++it) {
        int idx = it * 256 + tid;
        int r = idx >> 6, c = idx & 63;
        lds[r * 65 + c] = sigf(ntp[(nm0 + r) * 64 + c]);
    }
    __syncthreads();
    #pragma unroll
    for (int it = 0; it < 8; ++it) {
        int o = it * 256 + tid;
        int tpi = o >> 6, r = o & 63;
        f16x2 h;
        h[0] = (f16)lds[r * 65 + 2 * tpi];
        h[1] = (f16)lds[r * 65 + 2 * tpi + 1];
        out[tpi * NM + nm0 + r] = __builtin_bit_cast(u32, h);
    }
}

__global__ __launch_bounds__(1024) void grammar_fused(
    const float* __restrict__ x_all,
    const float* __restrict__ tp,
    const u32*  __restrict__ ntpT2,
    float* __restrict__ outp) {
    __shared__ float x_lds[LL * TT];
    __shared__ float prevbuf[2][NN];
    __shared__ u32 x2_lds[2][32];

    const int b = blockIdx.x;
    const int tid = threadIdx.x;
    const int lane16 = tid & 15;
    const int g = tid >> 4;
    const int mbase = lane16 * 8;

    const float* xb = x_all + b * (LL * TT);
    #pragma unroll
    for (int it = 0; it < 8; ++it) {
        int idx = it * 1024 + tid;
        x_lds[idx] = xb[idx];
    }
    __syncthreads();

    if (tid < NN) {
        float acc = 0.f;
        #pragma unroll 8
        for (int t = 0; t < TT; ++t)
            acc += sigf(tp[tid * TT + t]) * x_lds[t];
        prevbuf[0][tid] = acc;
    }
    __syncthreads();
    float out_r = 0.f;
    if (tid == 0) out_r = prevbuf[0][0];

    int p = 0;
    for (int i0 = 1; i0 < LL; i0 += 2) {
        const int ns = (LL - i0) >= 2 ? 2 : 1;
        if (tid < 64) {
            int s = tid >> 5, tpi = tid & 31;
            f16x2 h;
            if (s < ns) {
                h[0] = (f16)x_lds[(i0 + s) * TT + 2 * tpi];
                h[1] = (f16)x_lds[(i0 + s) * TT + 2 * tpi + 1];
            } else {
                h[0] = (f16)0.f; h[1] = (f16)0.f;
            }
            x2_lds[s][tpi] = __builtin_bit_cast(u32, h);
        }
        __syncthreads();

        float acc[2][2][8];
        #pragma unroll
        for (int k = 0; k < 2; ++k)
            #pragma unroll
            for (int s = 0; s < 2; ++s)
                #pragma unroll
                for (int j = 0; j < 8; ++j) acc[k][s][j] = 0.f;

        #pragma unroll 2
        for (int tpi = 0; tpi < 32; ++tpi) {
            f16x2 xv0 = __builtin_bit_cast(f16x2, x2_lds[0][tpi]);
            f16x2 xv1 = __builtin_bit_cast(f16x2, x2_lds[1][tpi]);
            const u32* base = ntpT2 + tpi * NM + 8 * tid;
            #pragma unroll
            for (int k = 0; k < 2; ++k) {
                uint4 w0 = *reinterpret_cast<const uint4*>(base + 8192 * k);
                uint4 w1 = *reinterpret_cast<const uint4*>(base + 8192 * k + 4);
                u32 wv[8] = {w0.x, w0.y, w0.z, w0.w, w1.x, w1.y, w1.z, w1.w};
                #pragma unroll
                for (int j = 0; j < 8; ++j) {
                    f16x2 w = __builtin_bit_cast(f16x2, wv[j]);
                    acc[k][0][j] = fdot2f(w, xv0, acc[k][0][j]);
                    acc[k][1][j] = fdot2f(w, xv1, acc[k][1][j]);
                }
            }
        }

        for (int s = 0; s < ns; ++s) {
            float4 pv0 = *reinterpret_cast<const float4*>(&prevbuf[p][mbase]);
            float4 pv1 = *reinterpret_cast<const float4*>(&prevbuf[p][mbase + 4]);
            float pvv[8] = {pv0.x, pv0.y, pv0.z, pv0.w, pv1.x, pv1.y, pv1.z, pv1.w};
            #pragma unroll
            for (int k = 0; k < 2; ++k) {
                float part = 0.f;
                #pragma unroll
                for (int j = 0; j < 8; ++j) {
                    float npcv = clip01(acc[k][s][j]);
                    part += npcv * pvv[j];
                }
                part += __shfl_xor(part, 1);
                part += __shfl_xor(part, 2);
                part += __shfl_xor(part, 4);
                part += __shfl_xor(part, 8);
                if (lane16 == 0) {
                    float c = clip01(part);
                    prevbuf[p ^ 1][g + 64 * k] = c;
                    if (tid == 0 && k == 0) {
                        float mask = x_lds[(i0 + s) * TT + 63];
                        out_r = out_r * mask + c * (1.f - mask);
                    }
                }
            }
            p ^= 1;
            __syncthreads();
        }
    }

    if (tid == 0) outp[b] = out_r;
}

// ---------------------------------------------------------------------------
extern "C" void kernel_launch(void* const* d_in, const int* in_sizes, int n_in,
                              void* d_out, int out_size, void* d_ws, size_t ws_size,
                              hipStream_t stream) {
    const float* input_tensor = (const float*)d_in[0];   // [64][128][64]
    const float* term_prod    = (const float*)d_in[1];   // [128][64]
    const float* nonterm_prod = (const float*)d_in[2];   // [128][128][64]
    float* outp = (float*)d_out;                         // [64]

    const size_t MB = 1024 * 1024;
    const size_t NPC_BYTES = 128 * MB;   // layout R
    const size_t WPK_BYTES = 2 * MB;     // bf16 A-frags
    const size_t XPK_BYTES = 1 * MB;     // bf16 B-frags

    if (ws_size >= NPC_BYTES + WPK_BYTES + XPK_BYTES + MB) {
        u8* npcbuf  = (u8*)d_ws;
        ushort* wpk = (ushort*)((char*)d_ws + NPC_BYTES);
        ushort* xpk = (ushort*)((char*)d_ws + NPC_BYTES + WPK_BYTES);
        pack_w<<<512, 256, 0, stream>>>(nonterm_prod, wpk);
        pack_x<<<256, 256, 0, stream>>>(input_tensor, xpk);
        gemm_mfma<<<1024, 256, 0, stream>>>(wpk, xpk, npcbuf);
        recur8<<<BB, 256, 0, stream>>>(input_tensor, term_prod, npcbuf, outp);
    } else {
        u32* ntpT2 = (u32*)d_ws;
        sig_transpose<<<256, 256, 0, stream>>>(nonterm_prod, ntpT2);
        grammar_fused<<<BB, 1024, 0, stream>>>(input_tensor, term_prod, ntpT2, outp);
    }
}

// Round 13
// 77.861 us; speedup vs baseline: 1.5561x; 1.0418x over previous
//
#include <hip/hip_runtime.h>
#include <hip/hip_bf16.h>

typedef unsigned int u32;
typedef unsigned char u8;
typedef _Float16 f16;
typedef f16 f16x2 __attribute__((ext_vector_type(2)));
typedef short s16x8 __attribute__((ext_vector_type(8)));
typedef float f32x4 __attribute__((ext_vector_type(4)));

#define BB 64
#define LL 128
#define TT 64
#define NN 128
#define NM (NN*NN)   // 16384

__device__ __forceinline__ float sigf(float v) {
    return 1.0f / (1.0f + __expf(-v));
}

__device__ __forceinline__ float clip01(float v) {
    return fminf(fmaxf(v, 0.f), 1.f);
}

__device__ __forceinline__ u32 f2bf(float f) {   // f32 -> bf16 bits (RNE)
    u32 u = __builtin_bit_cast(u32, f);
    return (u + 0x7fffu + ((u >> 16) & 1u)) >> 16;
}

__device__ __forceinline__ float fdot2f(f16x2 wa, f16x2 xa, float ca) {
#if defined(__HIP_DEVICE_COMPILE__) && __has_builtin(__builtin_amdgcn_fdot2)
    return __builtin_amdgcn_fdot2(wa, xa, ca, false);
#else
    return ca + (float)wa[0] * (float)xa[0] + (float)wa[1] * (float)xa[1];
#endif
}

__device__ __forceinline__ u32 ud4(u32 a, u32 b, u32 c) {   // 4x u8 dot + acc
#if defined(__HIP_DEVICE_COMPILE__) && __has_builtin(__builtin_amdgcn_udot4)
    return __builtin_amdgcn_udot4(a, b, c, false);
#else
    return c + (a & 255u) * (b & 255u) + ((a >> 8) & 255u) * ((b >> 8) & 255u)
             + ((a >> 16) & 255u) * ((b >> 16) & 255u) + (a >> 24) * (b >> 24);
#endif
}

// ---------------------------------------------------------------------------
// pack_wx: merged pack_w (bid<512) + pack_x (bid>=512).
__global__ __launch_bounds__(256) void pack_wx(const float* __restrict__ ntp,
                                               const float* __restrict__ x_all,
                                               ushort* __restrict__ wpk,
                                               ushort* __restrict__ xpk) {
    const int bid = blockIdx.x;
    if (bid < 512) {
        const int g = bid * 256 + threadIdx.x;   // 0..131071
        const int l = g & 63, h = (g >> 6) & 1, i = g >> 7;
        const int row = i * 16 + (l & 15);
        const int t0 = h * 32 + ((l >> 4) << 3);
        const float* src = ntp + row * 64 + t0;
        float4 f0 = *reinterpret_cast<const float4*>(src);
        float4 f1 = *reinterpret_cast<const float4*>(src + 4);
        float v[8] = {f0.x, f0.y, f0.z, f0.w, f1.x, f1.y, f1.z, f1.w};
        u32 o[4];
        #pragma unroll
        for (int q = 0; q < 4; ++q)
            o[q] = f2bf(sigf(v[2 * q])) | (f2bf(sigf(v[2 * q + 1])) << 16);
        uint4 ov; ov.x = o[0]; ov.y = o[1]; ov.z = o[2]; ov.w = o[3];
        *reinterpret_cast<uint4*>(wpk + (size_t)g * 8) = ov;
    } else {
        const int g = (bid - 512) * 256 + threadIdx.x;   // 0..65535
        const int l = g & 63, h = (g >> 6) & 1, j = (g >> 7) & 7, b = g >> 10;
        const int s = j * 16 + (l & 15);
        const int t0 = h * 32 + ((l >> 4) << 3);
        const float* src = x_all + ((size_t)b * LL + s) * TT + t0;
        float4 f0 = *reinterpret_cast<const float4*>(src);
        float4 f1 = *reinterpret_cast<const float4*>(src + 4);
        float v[8] = {f0.x, f0.y, f0.z, f0.w, f1.x, f1.y, f1.z, f1.w};
        u32 o[4];
        #pragma unroll
        for (int q = 0; q < 4; ++q)
            o[q] = f2bf(v[2 * q]) | (f2bf(v[2 * q + 1]) << 16);
        uint4 ov; ov.x = o[0]; ov.y = o[1]; ov.z = o[2]; ov.w = o[3];
        *reinterpret_cast<uint4*>(xpk + (size_t)g * 8) = ov;
    }
}

// ---------------------------------------------------------------------------
// gemm_mfma, layout R4 (u4 npc, 64 MB total):
//   npc byte(b,s,n,m) = b<<20 | (s>>4)<<17 | (s&15)<<13
//                       | ((m>>4) + 8*(n>>6))<<9 | (n&63)<<3 | (m&15)>>1
//   nibble: low = even m, high = odd m. q = round(15*clip01(.)).
// Store-side: wave-private LDS transpose (8 KB/wave, skewed), flush as
// 64 B full-line coalesced dwordx2 runs. Grid 1024 = (b 64) x (nb 16).
__global__ __launch_bounds__(256) void gemm_mfma(const ushort* __restrict__ wpk,
                                                 const ushort* __restrict__ xpk,
                                                 u8* __restrict__ npc) {
    __shared__ __align__(16) u8 stg[4][8192];
    const int b = blockIdx.x >> 4;
    const int nb = blockIdx.x & 15;
    const int wv = threadIdx.x >> 6, l = threadIdx.x & 63;

    uint4 xf[8][2];
    #pragma unroll
    for (int j = 0; j < 8; ++j)
        #pragma unroll
        for (int h = 0; h < 2; ++h)
            xf[j][h] = *reinterpret_cast<const uint4*>(
                xpk + (size_t)(((b * 8 + j) * 2 + h) * 64 + l) * 8);

    const int c = l & 15, r0 = (l >> 4) * 4;
    u8* stw = stg[wv];
    const int khi  = (nb >> 3) * 8;
    const int nlow = (nb & 7) * 8;

    for (int mg2 = 0; mg2 < 2; ++mg2) {
        const int mg = wv * 2 + mg2;
        #pragma unroll
        for (int n_l = 0; n_l < 8; ++n_l) {
            const int i = (nb * 8 + n_l) * 8 + mg;   // tile index
            uint4 a0 = *reinterpret_cast<const uint4*>(wpk + (size_t)((i * 2 + 0) * 64 + l) * 8);
            uint4 a1 = *reinterpret_cast<const uint4*>(wpk + (size_t)((i * 2 + 1) * 64 + l) * 8);
            const f32x4 z = {0.f, 0.f, 0.f, 0.f};
            f32x4 acc[8];
            #pragma unroll
            for (int j = 0; j < 8; ++j)
                acc[j] = __builtin_amdgcn_mfma_f32_16x16x32_bf16(
                    __builtin_bit_cast(s16x8, a0), __builtin_bit_cast(s16x8, xf[j][0]), z, 0, 0, 0);
            #pragma unroll
            for (int j = 0; j < 8; ++j)
                acc[j] = __builtin_amdgcn_mfma_f32_16x16x32_bf16(
                    __builtin_bit_cast(s16x8, a1), __builtin_bit_cast(s16x8, xf[j][1]), acc[j], 0, 0, 0);

            const int sk8 = ((n_l + c) & 7) << 3;   // skewed 8B slot
            #pragma unroll
            for (int j = 0; j < 8; ++j) {
                u32 q0 = (u32)(clip01(acc[j][0]) * 15.f + 0.5f);
                u32 q1 = (u32)(clip01(acc[j][1]) * 15.f + 0.5f);
                u32 q2 = (u32)(clip01(acc[j][2]) * 15.f + 0.5f);
                u32 q3 = (u32)(clip01(acc[j][3]) * 15.f + 0.5f);
                u32 hw = (q0 | (q1 << 4)) | ((q2 | (q3 << 4)) << 8);
                *reinterpret_cast<ushort*>(stw + j * 1024 + c * 64 + sk8 + (r0 >> 1)) = (ushort)hw;
            }
        }
        asm volatile("s_waitcnt lgkmcnt(0)" ::: "memory");
        __builtin_amdgcn_sched_barrier(0);

        // flush: 8 j x 2 rounds of 8-lane 64B full-line coalesced dwordx2
        #pragma unroll
        for (int j = 0; j < 8; ++j) {
            #pragma unroll
            for (int r = 0; r < 2; ++r) {
                const int slot = r * 64 + l;
                const int cc = slot >> 3;        // s-index 0..15
                const int nr = slot & 7;
                uint2 v = *reinterpret_cast<const uint2*>(
                    stw + j * 1024 + cc * 64 + (((nr + cc) & 7) << 3));
                *reinterpret_cast<uint2*>(npc + ((size_t)b << 20) + ((size_t)j << 17)
                    + ((size_t)cc << 13) + ((size_t)(mg + khi) << 9)
                    + ((nlow + nr) << 3)) = v;
            }
        }
        asm volatile("s_waitcnt lgkmcnt(0)" ::: "memory");
        __builtin_amdgcn_sched_barrier(0);
    }
}

// ---------------------------------------------------------------------------
// recur9: 256 threads (4 waves) per batch; thread (n = tid>>1, h = tid&1)
// owns 64 m's of row n: 4 x dwordx2 u4 loads/step (two 256B coalesced runs),
// 16 udot4 on nibble-unpacked words vs pre-packed even/odd prev bytes.
// prev stored directly in packed even/odd u32 form (byte writes at cur time,
// no extra barrier). Raw s_barrier + lgkmcnt-only drain; depth-4 prefetch.
__global__ __launch_bounds__(256, 1) void recur9(const float* __restrict__ x_all,
                                                 const float* __restrict__ tp,
                                                 const u8* __restrict__ npc,
                                                 float* __restrict__ outp) {
    // prev_pk[buf][0..15] = evens: word (mg*2+w) = prev[16mg+8w+{0,2,4,6}]
    // prev_pk[buf][16..31] = odds:  word (mg*2+w) = prev[16mg+8w+{1,3,5,7}]
    __shared__ u32 prev_pk[2][32];
    __shared__ float masks_lds[LL];
    __shared__ float tpc_lds[NN];
    __shared__ float x0_lds[TT];

    const int b = blockIdx.x, tid = threadIdx.x;
    const int n = tid >> 1, h = tid & 1;
    const u8* npcl = npc + ((size_t)b << 20)
                   + ((size_t)((n >> 6) * 8 + h * 4) << 9) + (u32)(n & 63) * 8;

    if (tid < 128) masks_lds[tid] = x_all[(size_t)b * 8192 + tid * 64 + 63];
    else if (tid < 192) x0_lds[tid - 128] = x_all[(size_t)b * 8192 + (tid - 128)];
    __syncthreads();

#define LOADSET(R, T) do { \
        int _t = (T) <= 127 ? (T) : 127; \
        const u8* _p = npcl + ((size_t)(_t >> 4) << 17) + ((size_t)(_t & 15) << 13); \
        R[0] = *reinterpret_cast<const uint2*>(_p); \
        R[1] = *reinterpret_cast<const uint2*>(_p + 512); \
        R[2] = *reinterpret_cast<const uint2*>(_p + 1024); \
        R[3] = *reinterpret_cast<const uint2*>(_p + 1536); \
        asm volatile("" ::: "memory"); \
    } while (0)

    uint2 nA[4], nB[4], nC[4], nD[4];
    LOADSET(nA, 1); LOADSET(nB, 2); LOADSET(nC, 3); LOADSET(nD, 4);

    // tpc (exact f32): thread tid < 128 computes row tid; hides prefetch
    float out_r = 0.f;
    if (tid < 128) {
        float a = 0.f;
        #pragma unroll
        for (int t4 = 0; t4 < 16; ++t4) {
            float4 xv = *reinterpret_cast<const float4*>(x0_lds + t4 * 4);
            float4 w0 = *reinterpret_cast<const float4*>(tp + tid * 64 + t4 * 4);
            a += sigf(w0.x) * xv.x; a += sigf(w0.y) * xv.y;
            a += sigf(w0.z) * xv.z; a += sigf(w0.w) * xv.w;
        }
        tpc_lds[tid] = a;
        if (tid == 0) out_r = a;            // out0 = tpc[0]
    }
    asm volatile("s_waitcnt lgkmcnt(0)" ::: "memory");
    __builtin_amdgcn_s_barrier();
    __builtin_amdgcn_sched_barrier(0);

    // packed-prev byte-write helper index for row n (h==0 threads)
    const int wr_idx  = ((n >> 4) << 1) + ((n >> 3) & 1) + ((n & 1) << 4);
    const int wr_byte = (n & 7) >> 1;

    // ---- step 1: cur1 = clip01(npc1 . tpc), tpc f32 (unclipped range) ----
    {
        float sf = 0.f;
        #pragma unroll
        for (int kk = 0; kk < 4; ++kk) {
            const int base_m = (4 * h + kk) * 16;
            u32 wlo = nA[kk].x, whi = nA[kk].y;
            #pragma unroll
            for (int by = 0; by < 4; ++by) {
                u32 b0 = (wlo >> (8 * by)) & 0xFFu;
                sf += (float)(b0 & 15u) * tpc_lds[base_m + 2 * by];
                sf += (float)(b0 >> 4)  * tpc_lds[base_m + 2 * by + 1];
                u32 b1 = (whi >> (8 * by)) & 0xFFu;
                sf += (float)(b1 & 15u) * tpc_lds[base_m + 8 + 2 * by];
                sf += (float)(b1 >> 4)  * tpc_lds[base_m + 8 + 2 * by + 1];
            }
        }
        float tot = sf + __shfl_xor(sf, 1);
        float c0 = clip01(tot * (1.f / 15.f));
        if (h == 0) {
            u32 q8 = (u32)(c0 * 255.f + 0.5f);
            ((u8*)&prev_pk[0][wr_idx])[wr_byte] = (u8)q8;
        }
        if (tid == 0) {
            float mk = masks_lds[1];
            out_r = out_r * mk + c0 * (1.f - mk);
        }
        asm volatile("s_waitcnt lgkmcnt(0)" ::: "memory");
        __builtin_amdgcn_s_barrier();
        __builtin_amdgcn_sched_barrier(0);
    }
    LOADSET(nA, 5);

    int p = 0;

#define STEP(R, S) do { \
        uint4 pe0 = *reinterpret_cast<const uint4*>(&prev_pk[p][8 * h]); \
        uint4 pe1 = *reinterpret_cast<const uint4*>(&prev_pk[p][8 * h + 4]); \
        uint4 po0 = *reinterpret_cast<const uint4*>(&prev_pk[p][16 + 8 * h]); \
        uint4 po1 = *reinterpret_cast<const uint4*>(&prev_pk[p][16 + 8 * h + 4]); \
        u32 PE[8] = {pe0.x, pe0.y, pe0.z, pe0.w, pe1.x, pe1.y, pe1.z, pe1.w}; \
        u32 PO[8] = {po0.x, po0.y, po0.z, po0.w, po1.x, po1.y, po1.z, po1.w}; \
        float mk = masks_lds[(S)]; \
        u32 ae = 0, ao = 0; \
        _Pragma("unroll") \
        for (int _kk = 0; _kk < 4; ++_kk) { \
            u32 _w0 = R[_kk].x, _w1 = R[_kk].y; \
            ae = ud4(_w0 & 0x0F0F0F0Fu, PE[2 * _kk], ae); \
            ao = ud4((_w0 >> 4) & 0x0F0F0F0Fu, PO[2 * _kk], ao); \
            ae = ud4(_w1 & 0x0F0F0F0Fu, PE[2 * _kk + 1], ae); \
            ao = ud4((_w1 >> 4) & 0x0F0F0F0Fu, PO[2 * _kk + 1], ao); \
        } \
        float sf = (float)(ae + ao); \
        float tot = sf + __shfl_xor(sf, 1); \
        float c0 = fminf(tot * (1.f / 3825.f), 1.f); \
        if (h == 0) { \
            u32 q8 = (u32)(c0 * 255.f + 0.5f); \
            ((u8*)&prev_pk[p ^ 1][wr_idx])[wr_byte] = (u8)q8; \
        } \
        if (tid == 0) out_r = out_r * mk + c0 * (1.f - mk); \
        asm volatile("s_waitcnt lgkmcnt(0)" ::: "memory"); \
        __builtin_amdgcn_s_barrier(); \
        __builtin_amdgcn_sched_barrier(0); \
        p ^= 1; \
    } while (0)

    // steps 2..125: 31 iterations x 4 steps, rotation B,C,D,A; loads 4 ahead
    for (int g = 0; g < 31; ++g) {
        const int s = 2 + 4 * g;
        STEP(nB, s);     LOADSET(nB, s + 4);
        STEP(nC, s + 1); LOADSET(nC, s + 5);
        STEP(nD, s + 2); LOADSET(nD, s + 6);
        STEP(nA, s + 3); LOADSET(nA, s + 7);
    }
    // tail: steps 126 (nB), 127 (nC); nD/nA hold dead clamped loads
    STEP(nB, 126);
    STEP(nC, 127);

#undef STEP
#undef LOADSET

    if (tid == 0) outp[b] = out_r;
}

// ---------------------------------------------------------------------------
// Fallback (known-passing round-2 kernel): fused recurrence, 2 MB ws.
__global__ __launch_bounds__(256) void sig_transpose(const float* __restrict__ ntp,
                                                     u32* __restrict__ out) {
    __shared__ float lds[64 * 65];
    const int nm0 = blockIdx.x * 64;
    const int tid = threadIdx.x;
    #pragma unroll
    for (int it = 0; it < 16; ++it) {
        int idx = it * 256 + tid;
        int r = idx >> 6, c = idx & 63;
        lds[r * 65 + c] = sigf(ntp[(nm0 + r) * 64 + c]);
    }
    __syncthreads();
    #pragma unroll
    for (int it = 0; it < 8; ++it) {
        int o = it * 256 + tid;
        int tpi = o >> 6, r = o & 63;
        f16x2 h;
        h[0] = (f16)lds[r * 65 + 2 * tpi];
        h[1] = (f16)lds[r * 65 + 2 * tpi + 1];
        out[tpi * NM + nm0 + r] = __builtin_bit_cast(u32, h);
    }
}

__global__ __launch_bounds__(1024) void grammar_fused(
    const float* __restrict__ x_all,
    const float* __restrict__ tp,
    const u32*  __restrict__ ntpT2,
    float* __restrict__ outp) {
    __shared__ float x_lds[LL * TT];
    __shared__ float prevbuf[2][NN];
    __shared__ u32 x2_lds[2][32];

    const int b = blockIdx.x;
    const int tid = threadIdx.x;
    const int lane16 = tid & 15;
    const int g = tid >> 4;
    const int mbase = lane16 * 8;

    const float* xb = x_all + b * (LL * TT);
    #pragma unroll
    for (int it = 0; it < 8; ++it) {
        int idx = it * 1024 + tid;
        x_lds[idx] = xb[idx];
    }
    __syncthreads();

    if (tid < NN) {
        float acc = 0.f;
        #pragma unroll 8
        for (int t = 0; t < TT; ++t)
            acc += sigf(tp[tid * TT + t]) * x_lds[t];
        prevbuf[0][tid] = acc;
    }
    __syncthreads();
    float out_r = 0.f;
    if (tid == 0) out_r = prevbuf[0][0];

    int p = 0;
    for (int i0 = 1; i0 < LL; i0 += 2) {
        const int ns = (LL - i0) >= 2 ? 2 : 1;
        if (tid < 64) {
            int s = tid >> 5, tpi = tid & 31;
            f16x2 h;
            if (s < ns) {
                h[0] = (f16)x_lds[(i0 + s) * TT + 2 * tpi];
                h[1] = (f16)x_lds[(i0 + s) * TT + 2 * tpi + 1];
            } else {
                h[0] = (f16)0.f; h[1] = (f16)0.f;
            }
            x2_lds[s][tpi] = __builtin_bit_cast(u32, h);
        }
        __syncthreads();

        float acc[2][2][8];
        #pragma unroll
        for (int k = 0; k < 2; ++k)
            #pragma unroll
            for (int s = 0; s < 2; ++s)
                #pragma unroll
                for (int j = 0; j < 8; ++j) acc[k][s][j] = 0.f;

        #pragma unroll 2
        for (int tpi = 0; tpi < 32; ++tpi) {
            f16x2 xv0 = __builtin_bit_cast(f16x2, x2_lds[0][tpi]);
            f16x2 xv1 = __builtin_bit_cast(f16x2, x2_lds[1][tpi]);
            const u32* base = ntpT2 + tpi * NM + 8 * tid;
            #pragma unroll
            for (int k = 0; k < 2; ++k) {
                uint4 w0 = *reinterpret_cast<const uint4*>(base + 8192 * k);
                uint4 w1 = *reinterpret_cast<const uint4*>(base + 8192 * k + 4);
                u32 wv[8] = {w0.x, w0.y, w0.z, w0.w, w1.x, w1.y, w1.z, w1.w};
                #pragma unroll
                for (int j = 0; j < 8; ++j) {
                    f16x2 w = __builtin_bit_cast(f16x2, wv[j]);
                    acc[k][0][j] = fdot2f(w, xv0, acc[k][0][j]);
                    acc[k][1][j] = fdot2f(w, xv1, acc[k][1][j]);
                }
            }
        }

        for (int s = 0; s < ns; ++s) {
            float4 pv0 = *reinterpret_cast<const float4*>(&prevbuf[p][mbase]);
            float4 pv1 = *reinterpret_cast<const float4*>(&prevbuf[p][mbase + 4]);
            float pvv[8] = {pv0.x, pv0.y, pv0.z, pv0.w, pv1.x, pv1.y, pv1.z, pv1.w};
            #pragma unroll
            for (int k = 0; k < 2; ++k) {
                float part = 0.f;
                #pragma unroll
                for (int j = 0; j < 8; ++j) {
                    float npcv = clip01(acc[k][s][j]);
                    part += npcv * pvv[j];
                }
                part += __shfl_xor(part, 1);
                part += __shfl_xor(part, 2);
                part += __shfl_xor(part, 4);
                part += __shfl_xor(part, 8);
                if (lane16 == 0) {
                    float c = clip01(part);
                    prevbuf[p ^ 1][g + 64 * k] = c;
                    if (tid == 0 && k == 0) {
                        float mask = x_lds[(i0 + s) * TT + 63];
                        out_r = out_r * mask + c * (1.f - mask);
                    }
                }
            }
            p ^= 1;
            __syncthreads();
        }
    }

    if (tid == 0) outp[b] = out_r;
}

// ---------------------------------------------------------------------------
extern "C" void kernel_launch(void* const* d_in, const int* in_sizes, int n_in,
                              void* d_out, int out_size, void* d_ws, size_t ws_size,
                              hipStream_t stream) {
    const float* input_tensor = (const float*)d_in[0];   // [64][128][64]
    const float* term_prod    = (const float*)d_in[1];   // [128][64]
    const float* nonterm_prod = (const float*)d_in[2];   // [128][128][64]
    float* outp = (float*)d_out;                         // [64]

    const size_t MB = 1024 * 1024;
    const size_t NPC_BYTES = 64 * MB;    // layout R4 (u4)
    const size_t WPK_BYTES = 2 * MB;     // bf16 A-frags
    const size_t XPK_BYTES = 1 * MB;     // bf16 B-frags

    if (ws_size >= NPC_BYTES + WPK_BYTES + XPK_BYTES + MB) {
        u8* npcbuf  = (u8*)d_ws;
        ushort* wpk = (ushort*)((char*)d_ws + NPC_BYTES);
        ushort* xpk = (ushort*)((char*)d_ws + NPC_BYTES + WPK_BYTES);
        pack_wx<<<768, 256, 0, stream>>>(nonterm_prod, input_tensor, wpk, xpk);
        gemm_mfma<<<1024, 256, 0, stream>>>(wpk, xpk, npcbuf);
        recur9<<<BB, 256, 0, stream>>>(input_tensor, term_prod, npcbuf, outp);
    } else {
        u32* ntpT2 = (u32*)d_ws;
        sig_transpose<<<256, 256, 0, stream>>>(nonterm_prod, ntpT2);
        grammar_fused<<<BB, 1024, 0, stream>>>(input_tensor, term_prod, ntpT2, outp);
    }
}